// Round 9
// baseline (196.909 us; speedup 1.0000x reference)
//
#include <hip/hip_runtime.h>
#include <stdint.h>

#define G_NUM 4096
#define WPB   4                 // sel: waves per block, 1 graph per wave
#define HBW   512               // sel: histogram buckets (9-bit radix: sign+exp+1 mant)
#define HSZ   528               // skewed physical size: HP(511)=526
#define CLSW  128               // boundary-class capacity
#define KCH   12                // max chunks with k16 staging (12*256=3072 elems)
#define KCAP  (KCH * 256)

typedef unsigned long long ull;

// wave-synchronous LDS fence (no s_barrier in sel kernel)
__device__ __forceinline__ void wsync() {
    asm volatile("s_waitcnt lgkmcnt(0)" ::: "memory");
}
__device__ __forceinline__ unsigned int order_bits(float f) {
    unsigned int b = __float_as_uint(f);
    return (b & 0x80000000u) ? ~b : (b | 0x80000000u);
}
// skewed LDS slot: consecutive buckets stay in distinct banks (atomics), and
// wave_sel's strided reads spread ~2 lanes/bank (free). Bijective.
__device__ __forceinline__ int HP(int b) { return b + (b >> 5); }

// ---------------- prep: start[] bsearch + gtile + mask dtype detect ----------------
// flag: 2 = byte (bool) mask, else 32-bit word mask (int/float nonzero)
__global__ void prep_kernel(const int* __restrict__ batch, int* __restrict__ start,
                            int* __restrict__ gtile, const unsigned int* __restrict__ mraw,
                            int* __restrict__ flag, int E, int ntiles) {
    if (blockIdx.x == 0 && threadIdx.x < 64) {
        int lane = threadIdx.x;
        bool allI = true, allF = true;
        for (int i = lane; i < 256; i += 64) {
            unsigned int w = mraw[i];
            if (w > 1u) allI = false;
            if (w != 0u && w != 0x3F800000u) allF = false;
        }
        allI = __all(allI);
        allF = __all(allF);
        if (lane == 0) *flag = (allI || allF) ? 0 : 2;
    }
    int t = blockIdx.x * blockDim.x + threadIdx.x;
    if (t <= G_NUM) {
        if (t == G_NUM) { start[G_NUM] = E; return; }
        int lo = 0, hi = E;                  // lower_bound: first i with batch[i] >= t
        while (lo < hi) {
            int mid = (lo + hi) >> 1;
            if (batch[mid] < t) lo = mid + 1; else hi = mid;
        }
        start[t] = lo;
    } else {
        int tt = t - (G_NUM + 1);
        if (tt < ntiles) gtile[tt] = batch[(size_t)tt << 10];   // graph of elem tt*1024
    }
}

// Wave-local k-th bucket select over NPT*64 buckets (lane owns [lane*NPT,+NPT),
// skew-mapped). Self-clears read slots. Returns wave-uniform results. No barriers.
template <int NPT>
__device__ __forceinline__ void wave_sel(unsigned int* hist, int lane, int kk,
                                         int& bsel, unsigned int& cgt, unsigned int& csel)
{
    unsigned int h[NPT];
    unsigned int S = 0u;
    const int b0 = lane * NPT;
    #pragma unroll
    for (int j = 0; j < NPT; ++j) {
        int pb = HP(b0 + j);
        h[j] = hist[pb]; S += h[j]; hist[pb] = 0u;
    }
    unsigned int v = S;
    #pragma unroll
    for (int off = 1; off < 64; off <<= 1) {
        unsigned int o = __shfl_down(v, off, 64);
        if (lane + off < 64) v += o;
    }
    unsigned int run = v - S;            // count in buckets strictly above my range
    int fj = -1; unsigned int fc = 0u, fs = 0u;
    #pragma unroll
    for (int j = NPT - 1; j >= 0; --j) {
        unsigned int inc = run + h[j];
        if (fj < 0 && (unsigned)kk <= inc && (unsigned)kk > run) { fj = j; fc = run; fs = h[j]; }
        run = inc;
    }
    ull bm = __ballot(fj >= 0);
    int wl = (int)(__ffsll((long long)bm) - 1);
    bsel = __shfl(b0 + fj, wl, 64);
    cgt  = __shfl(fc, wl, 64);
    csel = __shfl(fs, wl, 64);
}

// ---------------- sel: per-graph exact (P, licut), zero barriers ----------------
__global__ __launch_bounds__(256) void sel_kernel(
    const float* __restrict__ scores, const void* __restrict__ maskp,
    const int* __restrict__ start, const int* __restrict__ kp,
    const int* __restrict__ flagp, ull* __restrict__ PL)
{
    __shared__ unsigned int   hist_s[WPB][HSZ];
    __shared__ unsigned short k16_s[WPB][KCAP];
    __shared__ ull            cls_s[WPB][CLSW];
    __shared__ unsigned int   ccnt_s[WPB];

    const int tid  = threadIdx.x;
    const int lane = tid & 63;
    const int w    = tid >> 6;
    const int g    = blockIdx.x * WPB + w;

    const int s0 = start[g], s1 = start[g + 1], len = s1 - s0;
    if (len <= 0) return;                         // never queried by out_kernel
    const int k = *kp, mflag = *flagp;
    if (k <= 0) { if (!lane) PL[g] = (0xFFFFFFFFull << 32) | 0xFFFFFFFFull; return; }

    unsigned int*   hist = hist_s[w];
    unsigned short* k16  = k16_s[w];
    ull*            cls  = cls_s[w];

    const int a0 = s0 & ~3, dl = a0 - s0;
    const int nch = (s1 - a0 + 255) >> 8;
    const bool st16 = (nch <= KCH);

    #pragma unroll
    for (int j = 0; j < HBW / 64; ++j) hist[HP(lane + 64 * j)] = 0u;
    if (!lane) ccnt_s[w] = 0u;
    wsync();

    auto load_chunk = [&](int q, unsigned int kk4[4]) -> unsigned int {
        const int g0 = a0 + 4 * (q * 64 + lane);
        unsigned int cm4 = 0u;
        if (g0 >= s0 && g0 + 4 <= s1) {
            float4 f = *(const float4*)(scores + g0);
            kk4[0] = order_bits(f.x); kk4[1] = order_bits(f.y);
            kk4[2] = order_bits(f.z); kk4[3] = order_bits(f.w);
            if (mflag == 2) {
                unsigned int mw = *(const unsigned int*)((const unsigned char*)maskp + g0);
                if (mw & 0x000000FFu) cm4 |= 1u;
                if (mw & 0x0000FF00u) cm4 |= 2u;
                if (mw & 0x00FF0000u) cm4 |= 4u;
                if (mw & 0xFF000000u) cm4 |= 8u;
            } else {
                int4 mw = *(const int4*)((const int*)maskp + g0);
                if (mw.x) cm4 |= 1u; if (mw.y) cm4 |= 2u;
                if (mw.z) cm4 |= 4u; if (mw.w) cm4 |= 8u;
            }
        } else if (g0 < s1 && g0 + 4 > s0) {
            #pragma unroll
            for (int j = 0; j < 4; ++j) {
                int gi = g0 + j; kk4[j] = 0u;
                if (gi >= s0 && gi < s1) {
                    kk4[j] = order_bits(scores[gi]);
                    bool c = (mflag == 2) ? (((const unsigned char*)maskp)[gi] != 0)
                                          : (((const int*)maskp)[gi] != 0);
                    if (c) cm4 |= 1u << j;
                }
            }
        } else {
            kk4[0] = kk4[1] = kk4[2] = kk4[3] = 0u;
        }
        return cm4;
    };

    // ---- sweep 1: stream, histogram, optional 16-bit key staging ----
    int lc = 0;
    for (int q = 0; q < nch; ++q) {
        unsigned int kk4[4];
        unsigned int cm4 = load_chunk(q, kk4);
        if (st16) {
            ushort4 hv; unsigned short* hp = (unsigned short*)&hv;
            #pragma unroll
            for (int j = 0; j < 4; ++j) {
                unsigned int h = kk4[j] >> 16; h += (h == 0u);   // cand sentinel >=1
                hp[j] = ((cm4 >> j) & 1u) ? (unsigned short)h : (unsigned short)0;
            }
            *(ushort4*)&k16[4 * (q * 64 + lane)] = hv;
        }
        #pragma unroll
        for (int j = 0; j < 4; ++j)
            if ((cm4 >> j) & 1u) { atomicAdd(&hist[HP((int)(kk4[j] >> 23))], 1u); ++lc; }
    }
    #pragma unroll
    for (int off = 1; off < 64; off <<= 1) lc += __shfl_xor(lc, off, 64);
    const int m = lc;
    wsync();

    unsigned int P = 0u;
    int licut = 0x7FFFFFFF;

    if (m > k) {
        int bsel; unsigned int cgt, csel;
        wave_sel<HBW / 64>(hist, lane, k, bsel, cgt, csel);
        int kk2 = k - (int)cgt;                   // rank within selected bucket

        if (csel <= CLSW) {
            // ---- collect boundary class ----
            if (st16) {
                const int tot2 = (nch * 256) >> 1;
                const unsigned int* k16w = (const unsigned int*)k16;
                for (int i2 = lane; i2 < tot2; i2 += 64) {
                    unsigned int h2 = k16w[i2];
                    unsigned int h0 = h2 & 0xFFFFu, h1 = h2 >> 16;
                    if (h0 && (int)(h0 >> 7) == bsel) {
                        int lp = 2 * i2;
                        unsigned int key = order_bits(scores[a0 + lp]);
                        cls[atomicAdd(&ccnt_s[w], 1u)] = ((ull)key << 32) | (unsigned)(lp + dl);
                    }
                    if (h1 && (int)(h1 >> 7) == bsel) {
                        int lp = 2 * i2 + 1;
                        unsigned int key = order_bits(scores[a0 + lp]);
                        cls[atomicAdd(&ccnt_s[w], 1u)] = ((ull)key << 32) | (unsigned)(lp + dl);
                    }
                }
            } else {
                for (int q = 0; q < nch; ++q) {
                    unsigned int kk4[4];
                    unsigned int cm4 = load_chunk(q, kk4);
                    const int g0 = a0 + 4 * (q * 64 + lane);
                    #pragma unroll
                    for (int j = 0; j < 4; ++j)
                        if (((cm4 >> j) & 1u) && (int)(kk4[j] >> 23) == bsel)
                            cls[atomicAdd(&ccnt_s[w], 1u)] =
                                ((ull)kk4[j] << 32) | (unsigned)(g0 + j - s0);
                }
            }
            wsync();
            // ---- exact rank by (key32, li) ----
            bool found = false; unsigned int fP = 0u; int fL = 0;
            if (csel <= 64) {
                ull me = (lane < (int)csel) ? cls[lane] : 0ull;
                unsigned int mk = (unsigned int)(me >> 32), ml = (unsigned int)me;
                int r = 0;
                for (int j = 0; j < (int)csel; ++j) {
                    ull o = __shfl(me, j, 64);
                    unsigned int ok = (unsigned int)(o >> 32), ol = (unsigned int)o;
                    r += (ok > mk || (ok == mk && ol < ml)) ? 1 : 0;
                }
                if (lane < (int)csel && r == kk2 - 1) { found = true; fP = mk; fL = (int)ml; }
            } else {
                for (int e = lane; e < (int)csel; e += 64) {
                    ull me = cls[e];
                    unsigned int mk = (unsigned int)(me >> 32), ml = (unsigned int)me;
                    int r = 0;
                    for (int j = 0; j < (int)csel; ++j) {
                        ull o = cls[j];
                        unsigned int ok = (unsigned int)(o >> 32), ol = (unsigned int)o;
                        r += (ok > mk || (ok == mk && ol < ml)) ? 1 : 0;
                    }
                    if (r == kk2 - 1) { found = true; fP = mk; fL = (int)ml; }
                }
            }
            ull bm = __ballot(found);
            int wl = (int)(__ffsll((long long)bm) - 1);
            P = __shfl(fP, wl, 64); licut = __shfl(fL, wl, 64);
        } else {
            // ---- rare: refine remaining 23 key bits via global re-reads ----
            unsigned int pfx = ((unsigned int)bsel) << 23;
            const int lows[3] = {15, 7, 0};
            const int wids[3] = {8, 8, 7};
            for (int r = 0; r < 3; ++r) {
                const int L = lows[r], W = wids[r];
                const unsigned int dm = (1u << W) - 1u;
                wsync();
                for (int q = 0; q < nch; ++q) {
                    unsigned int kk4[4];
                    unsigned int cm4 = load_chunk(q, kk4);
                    #pragma unroll
                    for (int j = 0; j < 4; ++j)
                        if (((cm4 >> j) & 1u) && ((kk4[j] >> (L + W)) == (pfx >> (L + W))))
                            atomicAdd(&hist[HP((int)((kk4[j] >> L) & dm))], 1u);
                }
                wsync();
                int b2; unsigned int cg2, cs2;
                if (W == 8) wave_sel<4>(hist, lane, kk2, b2, cg2, cs2);
                else        wave_sel<2>(hist, lane, kk2, b2, cg2, cs2);
                pfx |= ((unsigned int)b2) << L;
                kk2 -= (int)cg2;
            }
            P = pfx;
            // li binary search among key==P (>CLSW identical keys)
            int lo2 = 0, hi2 = len - 1;
            while (lo2 < hi2) {
                int mid = (lo2 + hi2) >> 1;
                int cc = 0;
                for (int q = 0; q < nch; ++q) {
                    unsigned int kk4[4];
                    unsigned int cm4 = load_chunk(q, kk4);
                    const int g0 = a0 + 4 * (q * 64 + lane);
                    #pragma unroll
                    for (int j = 0; j < 4; ++j)
                        if (((cm4 >> j) & 1u) && kk4[j] == P && (g0 + j - s0) <= mid) ++cc;
                }
                #pragma unroll
                for (int off = 1; off < 64; off <<= 1) cc += __shfl_xor(cc, off, 64);
                if (cc >= kk2) hi2 = mid; else lo2 = mid + 1;
            }
            licut = lo2;
        }
    }
    if (!lane) PL[g] = ((ull)P << 32) | (unsigned int)licut;
}

// ---------------- out: pure streaming map (no LDS, no atomics, no barriers) ----------------
__global__ __launch_bounds__(256) void out_kernel(
    const float* __restrict__ scores, const void* __restrict__ maskp,
    const int* __restrict__ start, const int* __restrict__ gtile,
    const ull* __restrict__ PL, const int* __restrict__ flagp,
    float* __restrict__ out_mask, float* __restrict__ out_scores, int E)
{
    const int mflag = *flagp;
    const int nchunk = E >> 2;
    const int stride = gridDim.x * blockDim.x;
    for (int c = blockIdx.x * blockDim.x + threadIdx.x; c < nchunk; c += stride) {
        const int gi0 = c << 2;
        int g = gtile[gi0 >> 10];
        int sg = start[g], snext = start[g + 1];
        while (gi0 >= snext) { ++g; sg = snext; snext = start[g + 1]; }
        ull pl = PL[g];

        float4 f = *(const float4*)(scores + gi0);
        unsigned int cm4 = 0u;
        if (mflag == 2) {
            unsigned int mw = *(const unsigned int*)((const unsigned char*)maskp + gi0);
            if (mw & 0x000000FFu) cm4 |= 1u;
            if (mw & 0x0000FF00u) cm4 |= 2u;
            if (mw & 0x00FF0000u) cm4 |= 4u;
            if (mw & 0xFF000000u) cm4 |= 8u;
        } else {
            int4 mw = *(const int4*)((const int*)maskp + gi0);
            if (mw.x) cm4 |= 1u; if (mw.y) cm4 |= 2u;
            if (mw.z) cm4 |= 4u; if (mw.w) cm4 |= 8u;
        }
        float4 vm, vs;
        float* pm = (float*)&vm; float* ps = (float*)&vs;
        const float* pf = (const float*)&f;
        #pragma unroll
        for (int j = 0; j < 4; ++j) {
            int gi = gi0 + j;
            while (gi >= snext) { ++g; sg = snext; snext = start[g + 1]; pl = PL[g]; }
            unsigned int Pv = (unsigned int)(pl >> 32);
            int Lv = (int)(unsigned int)pl;
            unsigned int key = order_bits(pf[j]);
            int li = gi - sg;
            bool kept = ((cm4 >> j) & 1u) && (key > Pv || (key == Pv && li <= Lv));
            pm[j] = kept ? 1.0f : 0.0f;
            ps[j] = kept ? pf[j] : 0.0f;
        }
        *(float4*)(out_mask   + gi0) = vm;
        *(float4*)(out_scores + gi0) = vs;
    }
    if (blockIdx.x == 0 && threadIdx.x == 0 && (E & 3)) {   // scalar tail (E%4)
        for (int gi = E & ~3; gi < E; ++gi) {
            int g = gtile[gi >> 10];
            while (gi >= start[g + 1]) ++g;
            ull pl = PL[g];
            unsigned int Pv = (unsigned int)(pl >> 32);
            int Lv = (int)(unsigned int)pl;
            bool cand = (mflag == 2) ? (((const unsigned char*)maskp)[gi] != 0)
                                     : (((const int*)maskp)[gi] != 0);
            float sc = scores[gi];
            unsigned int key = order_bits(sc);
            int li = gi - start[g];
            bool kept = cand && (key > Pv || (key == Pv && li <= Lv));
            out_mask[gi]   = kept ? 1.0f : 0.0f;
            out_scores[gi] = kept ? sc : 0.0f;
        }
    }
}

extern "C" void kernel_launch(void* const* d_in, const int* in_sizes, int n_in,
                              void* d_out, int out_size, void* d_ws, size_t ws_size,
                              hipStream_t stream) {
    const float* scores = (const float*)d_in[0];
    const int*   batch  = (const int*)d_in[1];
    const void*  mask   = d_in[2];
    const int*   kp     = (const int*)d_in[4];
    const int    E      = in_sizes[0];

    float* out_mask   = (float*)d_out;
    float* out_scores = out_mask + E;

    const int ntiles = (E + 1023) >> 10;
    char* ws = (char*)d_ws;
    int* flag  = (int*)ws;                              // 4 B
    int* start = (int*)(ws + 4096);                     // (G_NUM+1)*4 = 16388 B
    int* gtile = (int*)(ws + 4096 + 16640);             // ntiles*4
    ull* PL    = (ull*)(ws + 4096 + 16640 + (((size_t)ntiles * 4 + 255) & ~(size_t)255));

    const int prep_threads = G_NUM + 1 + ntiles;
    prep_kernel<<<(prep_threads + 255) / 256, 256, 0, stream>>>(
        batch, start, gtile, (const unsigned int*)mask, flag, E, ntiles);
    sel_kernel<<<G_NUM / WPB, 256, 0, stream>>>(scores, mask, start, kp, flag, PL);
    const int nchunk = E >> 2;
    int oblocks = (nchunk + 255) / 256;
    if (oblocks > 2048) oblocks = 2048;
    out_kernel<<<oblocks, 256, 0, stream>>>(scores, mask, start, gtile, PL, flag,
                                            out_mask, out_scores, E);
}

// Round 10
// 66.979 us; speedup vs baseline: 2.9399x; 2.9399x over previous
//
#include <hip/hip_runtime.h>
#include <stdint.h>

#define G_NUM 4096
#define WPB   4                 // sel: waves per block, 1 graph per wave
#define HBW   1024              // sel: histogram buckets (10-bit radix: sign+exp+1 mant)
#define HSZ   1056              // skewed physical size: HP(1023)=1054
#define CLSW  128               // boundary-class capacity (expected ~45)

typedef unsigned long long ull;

// wave-synchronous LDS fence (no s_barrier in sel kernel)
__device__ __forceinline__ void wsync() {
    asm volatile("s_waitcnt lgkmcnt(0)" ::: "memory");
}
__device__ __forceinline__ unsigned int order_bits(float f) {
    unsigned int b = __float_as_uint(f);
    return (b & 0x80000000u) ? ~b : (b | 0x80000000u);
}
// skewed LDS slot: consecutive buckets -> distinct banks (atomics); wave_sel's
// 16-bucket strided reads land ~2 lanes/bank (free, m136). Bijective.
__device__ __forceinline__ int HP(int b) { return b + (b >> 5); }

// ---------------- prep: start[] bsearch + gtile + mask dtype detect ----------------
// flag: 2 = byte (bool) mask, else 32-bit word mask (int/float nonzero)
__global__ void prep_kernel(const int* __restrict__ batch, int* __restrict__ start,
                            int* __restrict__ gtile, const unsigned int* __restrict__ mraw,
                            int* __restrict__ flag, int E, int ntiles) {
    if (blockIdx.x == 0 && threadIdx.x < 64) {
        int lane = threadIdx.x;
        bool allI = true, allF = true;
        for (int i = lane; i < 256; i += 64) {
            unsigned int w = mraw[i];
            if (w > 1u) allI = false;
            if (w != 0u && w != 0x3F800000u) allF = false;
        }
        allI = __all(allI);
        allF = __all(allF);
        if (lane == 0) *flag = (allI || allF) ? 0 : 2;
    }
    int t = blockIdx.x * blockDim.x + threadIdx.x;
    if (t <= G_NUM) {
        if (t == G_NUM) { start[G_NUM] = E; return; }
        int lo = 0, hi = E;                  // lower_bound: first i with batch[i] >= t
        while (lo < hi) {
            int mid = (lo + hi) >> 1;
            if (batch[mid] < t) lo = mid + 1; else hi = mid;
        }
        start[t] = lo;
    } else {
        int tt = t - (G_NUM + 1);
        if (tt < ntiles) gtile[tt] = batch[(size_t)tt << 10];   // graph of elem tt*1024
    }
}

// Wave-local k-th bucket select over NPT*64 buckets (lane owns [lane*NPT,+NPT),
// skew-mapped). Self-clears read slots. Returns wave-uniform results. No barriers.
template <int NPT>
__device__ __forceinline__ void wave_sel(unsigned int* hist, int lane, int kk,
                                         int& bsel, unsigned int& cgt, unsigned int& csel)
{
    unsigned int h[NPT];
    unsigned int S = 0u;
    const int b0 = lane * NPT;
    #pragma unroll
    for (int j = 0; j < NPT; ++j) {
        int pb = HP(b0 + j);
        h[j] = hist[pb]; S += h[j]; hist[pb] = 0u;
    }
    unsigned int v = S;
    #pragma unroll
    for (int off = 1; off < 64; off <<= 1) {
        unsigned int o = __shfl_down(v, off, 64);
        if (lane + off < 64) v += o;
    }
    unsigned int run = v - S;            // count in buckets strictly above my range
    int fj = -1; unsigned int fc = 0u, fs = 0u;
    #pragma unroll
    for (int j = NPT - 1; j >= 0; --j) {
        unsigned int inc = run + h[j];
        if (fj < 0 && (unsigned)kk <= inc && (unsigned)kk > run) { fj = j; fc = run; fs = h[j]; }
        run = inc;
    }
    ull bm = __ballot(fj >= 0);
    int wl = (int)(__ffsll((long long)bm) - 1);
    bsel = __shfl(b0 + fj, wl, 64);
    cgt  = __shfl(fc, wl, 64);
    csel = __shfl(fs, wl, 64);
}

// ---------------- sel: per-graph exact (P, licut), zero barriers ----------------
__global__ __launch_bounds__(256) void sel_kernel(
    const float* __restrict__ scores, const void* __restrict__ maskp,
    const int* __restrict__ start, const int* __restrict__ kp,
    const int* __restrict__ flagp, ull* __restrict__ PL)
{
    __shared__ unsigned int hist_s[WPB][HSZ];
    __shared__ ull          cls_s[WPB][CLSW];
    __shared__ unsigned int ccnt_s[WPB];

    const int tid  = threadIdx.x;
    const int lane = tid & 63;
    const int w    = tid >> 6;
    const int g    = blockIdx.x * WPB + w;

    const int s0 = start[g], s1 = start[g + 1], len = s1 - s0;
    if (len <= 0) return;                         // never queried by out_kernel
    const int k = *kp, mflag = *flagp;
    if (k <= 0) { if (!lane) PL[g] = (0xFFFFFFFFull << 32) | 0xFFFFFFFFull; return; }

    unsigned int* hist = hist_s[w];
    ull*          cls  = cls_s[w];

    const int a0 = s0 & ~3;
    const int nch = (s1 - a0 + 255) >> 8;

    #pragma unroll
    for (int j = 0; j < HBW / 64; ++j) hist[HP(lane + 64 * j)] = 0u;
    if (!lane) ccnt_s[w] = 0u;
    wsync();

    auto load_chunk = [&](int q, unsigned int kk4[4]) -> unsigned int {
        const int g0 = a0 + 4 * (q * 64 + lane);
        unsigned int cm4 = 0u;
        if (g0 >= s0 && g0 + 4 <= s1) {
            float4 f = *(const float4*)(scores + g0);
            kk4[0] = order_bits(f.x); kk4[1] = order_bits(f.y);
            kk4[2] = order_bits(f.z); kk4[3] = order_bits(f.w);
            if (mflag == 2) {
                unsigned int mw = *(const unsigned int*)((const unsigned char*)maskp + g0);
                if (mw & 0x000000FFu) cm4 |= 1u;
                if (mw & 0x0000FF00u) cm4 |= 2u;
                if (mw & 0x00FF0000u) cm4 |= 4u;
                if (mw & 0xFF000000u) cm4 |= 8u;
            } else {
                int4 mw = *(const int4*)((const int*)maskp + g0);
                if (mw.x) cm4 |= 1u; if (mw.y) cm4 |= 2u;
                if (mw.z) cm4 |= 4u; if (mw.w) cm4 |= 8u;
            }
        } else if (g0 < s1 && g0 + 4 > s0) {
            #pragma unroll
            for (int j = 0; j < 4; ++j) {
                int gi = g0 + j; kk4[j] = 0u;
                if (gi >= s0 && gi < s1) {
                    kk4[j] = order_bits(scores[gi]);
                    bool c = (mflag == 2) ? (((const unsigned char*)maskp)[gi] != 0)
                                          : (((const int*)maskp)[gi] != 0);
                    if (c) cm4 |= 1u << j;
                }
            }
        } else {
            kk4[0] = kk4[1] = kk4[2] = kk4[3] = 0u;
        }
        return cm4;
    };

    // ---- sweep 1 (HBM): histogram on bucket = key>>22, count candidates ----
    int lc = 0;
    for (int q = 0; q < nch; ++q) {
        unsigned int kk4[4];
        unsigned int cm4 = load_chunk(q, kk4);
        #pragma unroll
        for (int j = 0; j < 4; ++j)
            if ((cm4 >> j) & 1u) { atomicAdd(&hist[HP((int)(kk4[j] >> 22))], 1u); ++lc; }
    }
    #pragma unroll
    for (int off = 1; off < 64; off <<= 1) lc += __shfl_xor(lc, off, 64);
    const int m = lc;
    wsync();

    unsigned int P = 0u;
    int licut = 0x7FFFFFFF;

    if (m > k) {
        int bsel; unsigned int cgt, csel;
        wave_sel<HBW / 64>(hist, lane, k, bsel, cgt, csel);
        int kk2 = k - (int)cgt;                   // rank within selected bucket

        if (csel <= CLSW) {
            // ---- sweep 2 (L2/L3-hot): collect boundary class ----
            for (int q = 0; q < nch; ++q) {
                unsigned int kk4[4];
                unsigned int cm4 = load_chunk(q, kk4);
                const int g0 = a0 + 4 * (q * 64 + lane);
                #pragma unroll
                for (int j = 0; j < 4; ++j)
                    if (((cm4 >> j) & 1u) && (int)(kk4[j] >> 22) == bsel)
                        cls[atomicAdd(&ccnt_s[w], 1u)] =
                            ((ull)kk4[j] << 32) | (unsigned)(g0 + j - s0);
            }
            wsync();
            // ---- exact rank by (key32, li) ----
            bool found = false; unsigned int fP = 0u; int fL = 0;
            if (csel <= 64) {
                ull me = (lane < (int)csel) ? cls[lane] : 0ull;
                unsigned int mk = (unsigned int)(me >> 32), ml = (unsigned int)me;
                int r = 0;
                for (int j = 0; j < (int)csel; ++j) {
                    ull o = __shfl(me, j, 64);
                    unsigned int ok = (unsigned int)(o >> 32), ol = (unsigned int)o;
                    r += (ok > mk || (ok == mk && ol < ml)) ? 1 : 0;
                }
                if (lane < (int)csel && r == kk2 - 1) { found = true; fP = mk; fL = (int)ml; }
            } else {
                for (int e = lane; e < (int)csel; e += 64) {
                    ull me = cls[e];
                    unsigned int mk = (unsigned int)(me >> 32), ml = (unsigned int)me;
                    int r = 0;
                    for (int j = 0; j < (int)csel; ++j) {
                        ull o = cls[j];       // broadcast read, conflict-free
                        unsigned int ok = (unsigned int)(o >> 32), ol = (unsigned int)o;
                        r += (ok > mk || (ok == mk && ol < ml)) ? 1 : 0;
                    }
                    if (r == kk2 - 1) { found = true; fP = mk; fL = (int)ml; }
                }
            }
            ull bm = __ballot(found);
            int wl = (int)(__ffsll((long long)bm) - 1);
            P = __shfl(fP, wl, 64); licut = __shfl(fL, wl, 64);
        } else {
            // ---- degenerate (>CLSW in one bucket): refine remaining 22 key bits ----
            unsigned int pfx = ((unsigned int)bsel) << 22;
            const int lows[3] = {14, 6, 0};
            const int wids[3] = {8, 8, 6};
            for (int r = 0; r < 3; ++r) {
                const int L = lows[r], W = wids[r];
                const unsigned int dm = (1u << W) - 1u;
                wsync();
                for (int q = 0; q < nch; ++q) {
                    unsigned int kk4[4];
                    unsigned int cm4 = load_chunk(q, kk4);
                    #pragma unroll
                    for (int j = 0; j < 4; ++j)
                        if (((cm4 >> j) & 1u) && ((kk4[j] >> (L + W)) == (pfx >> (L + W))))
                            atomicAdd(&hist[HP((int)((kk4[j] >> L) & dm))], 1u);
                }
                wsync();
                int b2; unsigned int cg2, cs2;
                if (W == 8) wave_sel<4>(hist, lane, kk2, b2, cg2, cs2);
                else        wave_sel<1>(hist, lane, kk2, b2, cg2, cs2);
                pfx |= ((unsigned int)b2) << L;
                kk2 -= (int)cg2;
            }
            P = pfx;
            // li binary search among key==P (>CLSW identical keys)
            int lo2 = 0, hi2 = len - 1;
            while (lo2 < hi2) {
                int mid = (lo2 + hi2) >> 1;
                int cc = 0;
                for (int q = 0; q < nch; ++q) {
                    unsigned int kk4[4];
                    unsigned int cm4 = load_chunk(q, kk4);
                    const int g0 = a0 + 4 * (q * 64 + lane);
                    #pragma unroll
                    for (int j = 0; j < 4; ++j)
                        if (((cm4 >> j) & 1u) && kk4[j] == P && (g0 + j - s0) <= mid) ++cc;
                }
                #pragma unroll
                for (int off = 1; off < 64; off <<= 1) cc += __shfl_xor(cc, off, 64);
                if (cc >= kk2) hi2 = mid; else lo2 = mid + 1;
            }
            licut = lo2;
        }
    }
    if (!lane) PL[g] = ((ull)P << 32) | (unsigned int)licut;
}

// ---------------- out: pure streaming map (no LDS, no atomics, no barriers) ----------------
__global__ __launch_bounds__(256) void out_kernel(
    const float* __restrict__ scores, const void* __restrict__ maskp,
    const int* __restrict__ start, const int* __restrict__ gtile,
    const ull* __restrict__ PL, const int* __restrict__ flagp,
    float* __restrict__ out_mask, float* __restrict__ out_scores, int E)
{
    const int mflag = *flagp;
    const int nchunk = E >> 2;
    const int stride = gridDim.x * blockDim.x;
    for (int c = blockIdx.x * blockDim.x + threadIdx.x; c < nchunk; c += stride) {
        const int gi0 = c << 2;
        int g = gtile[gi0 >> 10];
        int sg = start[g], snext = start[g + 1];
        while (gi0 >= snext) { ++g; sg = snext; snext = start[g + 1]; }
        ull pl = PL[g];

        float4 f = *(const float4*)(scores + gi0);
        unsigned int cm4 = 0u;
        if (mflag == 2) {
            unsigned int mw = *(const unsigned int*)((const unsigned char*)maskp + gi0);
            if (mw & 0x000000FFu) cm4 |= 1u;
            if (mw & 0x0000FF00u) cm4 |= 2u;
            if (mw & 0x00FF0000u) cm4 |= 4u;
            if (mw & 0xFF000000u) cm4 |= 8u;
        } else {
            int4 mw = *(const int4*)((const int*)maskp + gi0);
            if (mw.x) cm4 |= 1u; if (mw.y) cm4 |= 2u;
            if (mw.z) cm4 |= 4u; if (mw.w) cm4 |= 8u;
        }
        float4 vm, vs;
        float* pm = (float*)&vm; float* ps = (float*)&vs;
        const float* pf = (const float*)&f;
        #pragma unroll
        for (int j = 0; j < 4; ++j) {
            int gi = gi0 + j;
            while (gi >= snext) { ++g; sg = snext; snext = start[g + 1]; pl = PL[g]; }
            unsigned int Pv = (unsigned int)(pl >> 32);
            int Lv = (int)(unsigned int)pl;
            unsigned int key = order_bits(pf[j]);
            int li = gi - sg;
            bool kept = ((cm4 >> j) & 1u) && (key > Pv || (key == Pv && li <= Lv));
            pm[j] = kept ? 1.0f : 0.0f;
            ps[j] = kept ? pf[j] : 0.0f;
        }
        *(float4*)(out_mask   + gi0) = vm;
        *(float4*)(out_scores + gi0) = vs;
    }
    if (blockIdx.x == 0 && threadIdx.x == 0 && (E & 3)) {   // scalar tail (E%4)
        for (int gi = E & ~3; gi < E; ++gi) {
            int g = gtile[gi >> 10];
            while (gi >= start[g + 1]) ++g;
            ull pl = PL[g];
            unsigned int Pv = (unsigned int)(pl >> 32);
            int Lv = (int)(unsigned int)pl;
            bool cand = (mflag == 2) ? (((const unsigned char*)maskp)[gi] != 0)
                                     : (((const int*)maskp)[gi] != 0);
            float sc = scores[gi];
            unsigned int key = order_bits(sc);
            int li = gi - start[g];
            bool kept = cand && (key > Pv || (key == Pv && li <= Lv));
            out_mask[gi]   = kept ? 1.0f : 0.0f;
            out_scores[gi] = kept ? sc : 0.0f;
        }
    }
}

extern "C" void kernel_launch(void* const* d_in, const int* in_sizes, int n_in,
                              void* d_out, int out_size, void* d_ws, size_t ws_size,
                              hipStream_t stream) {
    const float* scores = (const float*)d_in[0];
    const int*   batch  = (const int*)d_in[1];
    const void*  mask   = d_in[2];
    const int*   kp     = (const int*)d_in[4];
    const int    E      = in_sizes[0];

    float* out_mask   = (float*)d_out;
    float* out_scores = out_mask + E;

    const int ntiles = (E + 1023) >> 10;
    char* ws = (char*)d_ws;
    int* flag  = (int*)ws;                              // 4 B
    int* start = (int*)(ws + 4096);                     // (G_NUM+1)*4
    int* gtile = (int*)(ws + 4096 + 16640);             // ntiles*4
    ull* PL    = (ull*)(ws + 4096 + 16640 + (((size_t)ntiles * 4 + 255) & ~(size_t)255));

    const int prep_threads = G_NUM + 1 + ntiles;
    prep_kernel<<<(prep_threads + 255) / 256, 256, 0, stream>>>(
        batch, start, gtile, (const unsigned int*)mask, flag, E, ntiles);
    sel_kernel<<<G_NUM / WPB, 256, 0, stream>>>(scores, mask, start, kp, flag, PL);
    const int nchunk = E >> 2;
    int oblocks = (nchunk + 255) / 256;
    if (oblocks > 2048) oblocks = 2048;
    out_kernel<<<oblocks, 256, 0, stream>>>(scores, mask, start, gtile, PL, flag,
                                            out_mask, out_scores, E);
}

// Round 11
// 63.874 us; speedup vs baseline: 3.0828x; 1.0486x over previous
//
#include <hip/hip_runtime.h>
#include <stdint.h>

#define G_NUM 4096
#define WPB   4                 // sel: waves per block, 1 graph per wave
#define KCH   12                // max 256-elem chunks staged (3072 elems)
#define KCAP  (KCH * 256)       // u16 slots per wave
#define HSZW  528               // skewed hist words (512 data words = 1024 u16 buckets)
#define CLSW  128               // boundary-class capacity (expected ~45)

typedef unsigned long long ull;

// wave-synchronous LDS fence (no s_barrier in sel kernel)
__device__ __forceinline__ void wsync() {
    asm volatile("s_waitcnt lgkmcnt(0)" ::: "memory");
}
__device__ __forceinline__ unsigned int order_bits(float f) {
    unsigned int b = __float_as_uint(f);
    return (b & 0x80000000u) ? ~b : (b | 0x80000000u);
}
// skewed word slot: spreads strided word reads across banks. Bijective, <HSZW.
__device__ __forceinline__ int HPw(int wd) { return wd + (wd >> 5); }

// ---------------- prep: start[] bsearch + gtile + mask dtype detect ----------------
__global__ void prep_kernel(const int* __restrict__ batch, int* __restrict__ start,
                            int* __restrict__ gtile, const unsigned int* __restrict__ mraw,
                            int* __restrict__ flag, int E, int ntiles) {
    if (blockIdx.x == 0 && threadIdx.x < 64) {
        int lane = threadIdx.x;
        bool allI = true, allF = true;
        for (int i = lane; i < 256; i += 64) {
            unsigned int w = mraw[i];
            if (w > 1u) allI = false;
            if (w != 0u && w != 0x3F800000u) allF = false;
        }
        allI = __all(allI);
        allF = __all(allF);
        if (lane == 0) *flag = (allI || allF) ? 0 : 2;
    }
    int t = blockIdx.x * blockDim.x + threadIdx.x;
    if (t <= G_NUM) {
        if (t == G_NUM) { start[G_NUM] = E; return; }
        int lo = 0, hi = E;
        while (lo < hi) {
            int mid = (lo + hi) >> 1;
            if (batch[mid] < t) lo = mid + 1; else hi = mid;
        }
        start[t] = lo;
    } else {
        int tt = t - (G_NUM + 1);
        if (tt < ntiles) gtile[tt] = batch[(size_t)tt << 10];
    }
}

// u32-bucket k-th select over NPT*64 buckets (word==bucket, skew-mapped). Self-clears.
template <int NPT>
__device__ __forceinline__ void wave_selw(unsigned int* hist, int lane, int kk,
                                          int& bsel, unsigned int& cgt, unsigned int& csel)
{
    unsigned int h[NPT];
    unsigned int S = 0u;
    const int b0 = lane * NPT;
    #pragma unroll
    for (int j = 0; j < NPT; ++j) {
        int pw = HPw(b0 + j);
        h[j] = hist[pw]; S += h[j]; hist[pw] = 0u;
    }
    unsigned int v = S;
    #pragma unroll
    for (int off = 1; off < 64; off <<= 1) {
        unsigned int o = __shfl_down(v, off, 64);
        if (lane + off < 64) v += o;
    }
    unsigned int run = v - S;
    int fj = -1; unsigned int fc = 0u, fs = 0u;
    #pragma unroll
    for (int j = NPT - 1; j >= 0; --j) {
        unsigned int inc = run + h[j];
        if (fj < 0 && (unsigned)kk <= inc && (unsigned)kk > run) { fj = j; fc = run; fs = h[j]; }
        run = inc;
    }
    ull bm = __ballot(fj >= 0);
    int wl = (int)(__ffsll((long long)bm) - 1);
    bsel = __shfl(b0 + fj, wl, 64);
    cgt  = __shfl(fc, wl, 64);
    csel = __shfl(fs, wl, 64);
}

// 1024 u16-packed buckets (word b>>1, half b&1). Lane owns buckets [16*lane,+16).
__device__ __forceinline__ void wave_sel1024(unsigned int* hist, int lane, int kk,
                                             int& bsel, unsigned int& cgt, unsigned int& csel)
{
    unsigned int hw[8];
    unsigned int S = 0u;
    const int w0 = lane * 8;
    #pragma unroll
    for (int j = 0; j < 8; ++j) {
        int pw = HPw(w0 + j);
        hw[j] = hist[pw]; hist[pw] = 0u;
        S += (hw[j] & 0xFFFFu) + (hw[j] >> 16);
    }
    unsigned int v = S;
    #pragma unroll
    for (int off = 1; off < 64; off <<= 1) {
        unsigned int o = __shfl_down(v, off, 64);
        if (lane + off < 64) v += o;
    }
    unsigned int run = v - S;
    int fj = -1; unsigned int fc = 0u, fs = 0u;
    #pragma unroll
    for (int j = 15; j >= 0; --j) {
        unsigned int c = (j & 1) ? (hw[j >> 1] >> 16) : (hw[j >> 1] & 0xFFFFu);
        unsigned int inc = run + c;
        if (fj < 0 && (unsigned)kk <= inc && (unsigned)kk > run) { fj = j; fc = run; fs = c; }
        run = inc;
    }
    ull bm = __ballot(fj >= 0);
    int wl = (int)(__ffsll((long long)bm) - 1);
    bsel = __shfl(lane * 16 + fj, wl, 64);
    cgt  = __shfl(fc, wl, 64);
    csel = __shfl(fs, wl, 64);
}

// ---------------- sel: per-graph exact (P, licut), zero barriers ----------------
__global__ __launch_bounds__(256) void sel_kernel(
    const float* __restrict__ scores, const void* __restrict__ maskp,
    const int* __restrict__ start, const int* __restrict__ kp,
    const int* __restrict__ flagp, ull* __restrict__ PL)
{
    __shared__ unsigned int   hist_s[WPB][HSZW];
    __shared__ unsigned short k16_s[WPB][KCAP];
    __shared__ ull            cls_s[WPB][CLSW];
    __shared__ unsigned int   ccnt_s[WPB];

    const int tid  = threadIdx.x;
    const int lane = tid & 63;
    const int w    = tid >> 6;
    const int g    = blockIdx.x * WPB + w;

    const int s0 = start[g], s1 = start[g + 1], len = s1 - s0;
    if (len <= 0) return;                         // never queried by out_kernel
    const int k = *kp, mflag = *flagp;
    if (k <= 0) { if (!lane) PL[g] = (0xFFFFFFFFull << 32) | 0xFFFFFFFFull; return; }

    unsigned int*   hist = hist_s[w];
    unsigned short* k16  = k16_s[w];
    ull*            cls  = cls_s[w];

    const int a0 = s0 & ~3, dl = a0 - s0;
    const int nch = (s1 - a0 + 255) >> 8;

    #pragma unroll
    for (int j = 0; j < 9; ++j) { int idx = lane + 64 * j; if (idx < HSZW) hist[idx] = 0u; }
    if (!lane) ccnt_s[w] = 0u;
    wsync();

    // plain per-chunk loader (degenerate/fallback paths only)
    auto load_chunk = [&](int q, unsigned int kk4[4]) -> unsigned int {
        const int g0 = a0 + 4 * (q * 64 + lane);
        unsigned int cm4 = 0u;
        if (g0 >= s0 && g0 + 4 <= s1) {
            float4 f = *(const float4*)(scores + g0);
            kk4[0] = order_bits(f.x); kk4[1] = order_bits(f.y);
            kk4[2] = order_bits(f.z); kk4[3] = order_bits(f.w);
            if (mflag == 2) {
                unsigned int mw = *(const unsigned int*)((const unsigned char*)maskp + g0);
                if (mw & 0x000000FFu) cm4 |= 1u;
                if (mw & 0x0000FF00u) cm4 |= 2u;
                if (mw & 0x00FF0000u) cm4 |= 4u;
                if (mw & 0xFF000000u) cm4 |= 8u;
            } else {
                int4 mw = *(const int4*)((const int*)maskp + g0);
                if (mw.x) cm4 |= 1u; if (mw.y) cm4 |= 2u;
                if (mw.z) cm4 |= 4u; if (mw.w) cm4 |= 8u;
            }
        } else if (g0 < s1 && g0 + 4 > s0) {
            #pragma unroll
            for (int j = 0; j < 4; ++j) {
                int gi = g0 + j; kk4[j] = 0u;
                if (gi >= s0 && gi < s1) {
                    kk4[j] = order_bits(scores[gi]);
                    bool c = (mflag == 2) ? (((const unsigned char*)maskp)[gi] != 0)
                                          : (((const int*)maskp)[gi] != 0);
                    if (c) cm4 |= 1u << j;
                }
            }
        } else {
            kk4[0] = kk4[1] = kk4[2] = kk4[3] = 0u;
        }
        return cm4;
    };

    unsigned int P = 0u;
    int licut = 0x7FFFFFFF;

    if (nch <= KCH) {
        // ======== staged path: single pipelined sweep + LDS k16 ========
        int lc = 0;
        #pragma unroll
        for (int qb = 0; qb < KCH; qb += 4) {
            if (qb < nch) {
                float4 fs[4]; int4 mi[4]; unsigned int mb[4]; int typ[4];
                // ---- stage: issue all loads of 4 chunks before consuming ----
                #pragma unroll
                for (int j = 0; j < 4; ++j) {
                    const int q = qb + j;
                    const int g0 = a0 + 4 * (q * 64 + lane);
                    typ[j] = 2;
                    fs[j] = make_float4(0.f, 0.f, 0.f, 0.f);
                    mb[j] = 0u; mi[j] = make_int4(0, 0, 0, 0);
                    if (q < nch) {
                        if (g0 >= s0 && g0 + 4 <= s1) {
                            typ[j] = 0;
                            fs[j] = *(const float4*)(scores + g0);
                            if (mflag == 2)
                                mb[j] = *(const unsigned int*)((const unsigned char*)maskp + g0);
                            else
                                mi[j] = *(const int4*)((const int*)maskp + g0);
                        } else if (g0 < s1 && g0 + 4 > s0) {
                            typ[j] = 1;
                            float* pf = (float*)&fs[j];
                            int*   pm = (int*)&mi[j];
                            #pragma unroll
                            for (int e = 0; e < 4; ++e) {
                                int gi = g0 + e;
                                if (gi >= s0 && gi < s1) {
                                    pf[e] = scores[gi];
                                    bool c = (mflag == 2) ? (((const unsigned char*)maskp)[gi] != 0)
                                                          : (((const int*)maskp)[gi] != 0);
                                    pm[e] = c ? 1 : 0;
                                }
                            }
                        }
                    }
                }
                // ---- consume 4 chunks ----
                #pragma unroll
                for (int j = 0; j < 4; ++j) {
                    const int q = qb + j;
                    unsigned int cm4 = 0u;
                    if (typ[j] == 0) {
                        if (mflag == 2) {
                            if (mb[j] & 0x000000FFu) cm4 |= 1u;
                            if (mb[j] & 0x0000FF00u) cm4 |= 2u;
                            if (mb[j] & 0x00FF0000u) cm4 |= 4u;
                            if (mb[j] & 0xFF000000u) cm4 |= 8u;
                        } else {
                            if (mi[j].x) cm4 |= 1u; if (mi[j].y) cm4 |= 2u;
                            if (mi[j].z) cm4 |= 4u; if (mi[j].w) cm4 |= 8u;
                        }
                    } else if (typ[j] == 1) {
                        if (mi[j].x) cm4 |= 1u; if (mi[j].y) cm4 |= 2u;
                        if (mi[j].z) cm4 |= 4u; if (mi[j].w) cm4 |= 8u;
                    }
                    const float* pf = (const float*)&fs[j];
                    ushort4 hv; unsigned short* hp = (unsigned short*)&hv;
                    #pragma unroll
                    for (int e = 0; e < 4; ++e) {
                        unsigned int key = order_bits(pf[e]);
                        unsigned int h = key >> 16; h += (h == 0u);   // cand sentinel >=1
                        bool c = (cm4 >> e) & 1u;
                        hp[e] = c ? (unsigned short)h : (unsigned short)0;
                        if (c) {
                            atomicAdd(&hist[HPw((int)(h >> 7))], 1u << (((h >> 6) & 1u) << 4));
                            ++lc;
                        }
                    }
                    if (q < nch) *(ushort4*)&k16[4 * (q * 64 + lane)] = hv;
                }
            }
        }
        #pragma unroll
        for (int off = 1; off < 64; off <<= 1) lc += __shfl_xor(lc, off, 64);
        const int m = lc;
        wsync();

        if (m > k) {
            int bsel; unsigned int cgt, csel;
            wave_sel1024(hist, lane, k, bsel, cgt, csel);
            int kk2 = k - (int)cgt;

            if (csel <= CLSW) {
                // ---- scan LDS k16 for bucket members; gather exact keys from L2/L3 ----
                const int nw32 = nch * 128;
                const unsigned int* k16w = (const unsigned int*)k16;
                for (int i2 = lane; i2 < nw32; i2 += 64) {
                    unsigned int h2 = k16w[i2];
                    unsigned int h0 = h2 & 0xFFFFu, h1 = h2 >> 16;
                    if (h0 && (int)(h0 >> 6) == bsel) {
                        int lp = 2 * i2;
                        unsigned int key = order_bits(scores[a0 + lp]);
                        cls[atomicAdd(&ccnt_s[w], 1u)] = ((ull)key << 32) | (unsigned)(lp + dl);
                    }
                    if (h1 && (int)(h1 >> 6) == bsel) {
                        int lp = 2 * i2 + 1;
                        unsigned int key = order_bits(scores[a0 + lp]);
                        cls[atomicAdd(&ccnt_s[w], 1u)] = ((ull)key << 32) | (unsigned)(lp + dl);
                    }
                }
                wsync();
                bool found = false; unsigned int fP = 0u; int fL = 0;
                if (csel <= 64) {
                    ull me = (lane < (int)csel) ? cls[lane] : 0ull;
                    unsigned int mk = (unsigned int)(me >> 32), ml = (unsigned int)me;
                    int r = 0;
                    for (int j = 0; j < (int)csel; ++j) {
                        ull o = __shfl(me, j, 64);
                        unsigned int ok = (unsigned int)(o >> 32), ol = (unsigned int)o;
                        r += (ok > mk || (ok == mk && ol < ml)) ? 1 : 0;
                    }
                    if (lane < (int)csel && r == kk2 - 1) { found = true; fP = mk; fL = (int)ml; }
                } else {
                    for (int e = lane; e < (int)csel; e += 64) {
                        ull me = cls[e];
                        unsigned int mk = (unsigned int)(me >> 32), ml = (unsigned int)me;
                        int r = 0;
                        for (int j = 0; j < (int)csel; ++j) {
                            ull o = cls[j];
                            unsigned int ok = (unsigned int)(o >> 32), ol = (unsigned int)o;
                            r += (ok > mk || (ok == mk && ol < ml)) ? 1 : 0;
                        }
                        if (r == kk2 - 1) { found = true; fP = mk; fL = (int)ml; }
                    }
                }
                ull bm = __ballot(found);
                int wl = (int)(__ffsll((long long)bm) - 1);
                P = __shfl(fP, wl, 64); licut = __shfl(fL, wl, 64);
            } else {
                // ---- degenerate: refine remaining 22 key bits via global re-reads ----
                unsigned int pfx = ((unsigned int)bsel) << 22;
                const int lows[3] = {14, 6, 0};
                const int wids[3] = {8, 8, 6};
                for (int r = 0; r < 3; ++r) {
                    const int L = lows[r], W = wids[r];
                    const unsigned int dm = (1u << W) - 1u;
                    wsync();
                    for (int q = 0; q < nch; ++q) {
                        unsigned int kk4[4];
                        unsigned int cm4 = load_chunk(q, kk4);
                        #pragma unroll
                        for (int j = 0; j < 4; ++j)
                            if (((cm4 >> j) & 1u) && ((kk4[j] >> (L + W)) == (pfx >> (L + W))))
                                atomicAdd(&hist[HPw((int)((kk4[j] >> L) & dm))], 1u);
                    }
                    wsync();
                    int b2; unsigned int cg2, cs2;
                    if (W == 8) wave_selw<4>(hist, lane, kk2, b2, cg2, cs2);
                    else        wave_selw<1>(hist, lane, kk2, b2, cg2, cs2);
                    pfx |= ((unsigned int)b2) << L;
                    kk2 -= (int)cg2;
                }
                P = pfx;
                int lo2 = 0, hi2 = len - 1;
                while (lo2 < hi2) {
                    int mid = (lo2 + hi2) >> 1;
                    int cc = 0;
                    for (int q = 0; q < nch; ++q) {
                        unsigned int kk4[4];
                        unsigned int cm4 = load_chunk(q, kk4);
                        const int g0 = a0 + 4 * (q * 64 + lane);
                        #pragma unroll
                        for (int j = 0; j < 4; ++j)
                            if (((cm4 >> j) & 1u) && kk4[j] == P && (g0 + j - s0) <= mid) ++cc;
                    }
                    #pragma unroll
                    for (int off = 1; off < 64; off <<= 1) cc += __shfl_xor(cc, off, 64);
                    if (cc >= kk2) hi2 = mid; else lo2 = mid + 1;
                }
                licut = lo2;
            }
        }
    } else {
        // ======== fallback: two-sweep 10-bit + refine (len > 3069; ~never) ========
        int lc = 0;
        for (int q = 0; q < nch; ++q) {
            unsigned int kk4[4];
            unsigned int cm4 = load_chunk(q, kk4);
            #pragma unroll
            for (int j = 0; j < 4; ++j)
                if ((cm4 >> j) & 1u) { atomicAdd(&hist[HPw((int)(kk4[j] >> 24))], 1u); ++lc; }
        }
        #pragma unroll
        for (int off = 1; off < 64; off <<= 1) lc += __shfl_xor(lc, off, 64);
        const int m = lc;
        wsync();
        if (m > k) {
            int bsel; unsigned int cgt, csel;
            wave_selw<4>(hist, lane, k, bsel, cgt, csel);
            int kk2 = k - (int)cgt;
            unsigned int pfx = ((unsigned int)bsel) << 24;
            const int lows[3] = {16, 8, 0};
            for (int r = 0; r < 3; ++r) {
                const int L = lows[r];
                wsync();
                for (int q = 0; q < nch; ++q) {
                    unsigned int kk4[4];
                    unsigned int cm4 = load_chunk(q, kk4);
                    #pragma unroll
                    for (int j = 0; j < 4; ++j)
                        if (((cm4 >> j) & 1u) && ((kk4[j] >> (L + 8)) == (pfx >> (L + 8))))
                            atomicAdd(&hist[HPw((int)((kk4[j] >> L) & 0xFFu))], 1u);
                }
                wsync();
                int b2; unsigned int cg2, cs2;
                wave_selw<4>(hist, lane, kk2, b2, cg2, cs2);
                pfx |= ((unsigned int)b2) << L;
                kk2 -= (int)cg2;
            }
            P = pfx;
            int lo2 = 0, hi2 = len - 1;
            while (lo2 < hi2) {
                int mid = (lo2 + hi2) >> 1;
                int cc = 0;
                for (int q = 0; q < nch; ++q) {
                    unsigned int kk4[4];
                    unsigned int cm4 = load_chunk(q, kk4);
                    const int g0 = a0 + 4 * (q * 64 + lane);
                    #pragma unroll
                    for (int j = 0; j < 4; ++j)
                        if (((cm4 >> j) & 1u) && kk4[j] == P && (g0 + j - s0) <= mid) ++cc;
                }
                #pragma unroll
                for (int off = 1; off < 64; off <<= 1) cc += __shfl_xor(cc, off, 64);
                if (cc >= kk2) hi2 = mid; else lo2 = mid + 1;
            }
            licut = lo2;
        }
    }
    if (!lane) PL[g] = ((ull)P << 32) | (unsigned int)licut;
}

// ---------------- out: pure streaming map (no LDS, no atomics, no barriers) ----------------
__global__ __launch_bounds__(256) void out_kernel(
    const float* __restrict__ scores, const void* __restrict__ maskp,
    const int* __restrict__ start, const int* __restrict__ gtile,
    const ull* __restrict__ PL, const int* __restrict__ flagp,
    float* __restrict__ out_mask, float* __restrict__ out_scores, int E)
{
    const int mflag = *flagp;
    const int nchunk = E >> 2;
    const int stride = gridDim.x * blockDim.x;
    for (int c = blockIdx.x * blockDim.x + threadIdx.x; c < nchunk; c += stride) {
        const int gi0 = c << 2;
        int g = gtile[gi0 >> 10];
        int sg = start[g], snext = start[g + 1];
        while (gi0 >= snext) { ++g; sg = snext; snext = start[g + 1]; }
        ull pl = PL[g];

        float4 f = *(const float4*)(scores + gi0);
        unsigned int cm4 = 0u;
        if (mflag == 2) {
            unsigned int mw = *(const unsigned int*)((const unsigned char*)maskp + gi0);
            if (mw & 0x000000FFu) cm4 |= 1u;
            if (mw & 0x0000FF00u) cm4 |= 2u;
            if (mw & 0x00FF0000u) cm4 |= 4u;
            if (mw & 0xFF000000u) cm4 |= 8u;
        } else {
            int4 mw = *(const int4*)((const int*)maskp + gi0);
            if (mw.x) cm4 |= 1u; if (mw.y) cm4 |= 2u;
            if (mw.z) cm4 |= 4u; if (mw.w) cm4 |= 8u;
        }
        float4 vm, vs;
        float* pm = (float*)&vm; float* ps = (float*)&vs;
        const float* pf = (const float*)&f;
        #pragma unroll
        for (int j = 0; j < 4; ++j) {
            int gi = gi0 + j;
            while (gi >= snext) { ++g; sg = snext; snext = start[g + 1]; pl = PL[g]; }
            unsigned int Pv = (unsigned int)(pl >> 32);
            int Lv = (int)(unsigned int)pl;
            unsigned int key = order_bits(pf[j]);
            int li = gi - sg;
            bool kept = ((cm4 >> j) & 1u) && (key > Pv || (key == Pv && li <= Lv));
            pm[j] = kept ? 1.0f : 0.0f;
            ps[j] = kept ? pf[j] : 0.0f;
        }
        *(float4*)(out_mask   + gi0) = vm;
        *(float4*)(out_scores + gi0) = vs;
    }
    if (blockIdx.x == 0 && threadIdx.x == 0 && (E & 3)) {
        for (int gi = E & ~3; gi < E; ++gi) {
            int g = gtile[gi >> 10];
            while (gi >= start[g + 1]) ++g;
            ull pl = PL[g];
            unsigned int Pv = (unsigned int)(pl >> 32);
            int Lv = (int)(unsigned int)pl;
            bool cand = (mflag == 2) ? (((const unsigned char*)maskp)[gi] != 0)
                                     : (((const int*)maskp)[gi] != 0);
            float sc = scores[gi];
            unsigned int key = order_bits(sc);
            int li = gi - start[g];
            bool kept = cand && (key > Pv || (key == Pv && li <= Lv));
            out_mask[gi]   = kept ? 1.0f : 0.0f;
            out_scores[gi] = kept ? sc : 0.0f;
        }
    }
}

extern "C" void kernel_launch(void* const* d_in, const int* in_sizes, int n_in,
                              void* d_out, int out_size, void* d_ws, size_t ws_size,
                              hipStream_t stream) {
    const float* scores = (const float*)d_in[0];
    const int*   batch  = (const int*)d_in[1];
    const void*  mask   = d_in[2];
    const int*   kp     = (const int*)d_in[4];
    const int    E      = in_sizes[0];

    float* out_mask   = (float*)d_out;
    float* out_scores = out_mask + E;

    const int ntiles = (E + 1023) >> 10;
    char* ws = (char*)d_ws;
    int* flag  = (int*)ws;
    int* start = (int*)(ws + 4096);
    int* gtile = (int*)(ws + 4096 + 16640);
    ull* PL    = (ull*)(ws + 4096 + 16640 + (((size_t)ntiles * 4 + 255) & ~(size_t)255));

    const int prep_threads = G_NUM + 1 + ntiles;
    prep_kernel<<<(prep_threads + 255) / 256, 256, 0, stream>>>(
        batch, start, gtile, (const unsigned int*)mask, flag, E, ntiles);
    sel_kernel<<<G_NUM / WPB, 256, 0, stream>>>(scores, mask, start, kp, flag, PL);
    const int nchunk = E >> 2;
    int oblocks = (nchunk + 255) / 256;
    if (oblocks > 2048) oblocks = 2048;
    out_kernel<<<oblocks, 256, 0, stream>>>(scores, mask, start, gtile, PL, flag,
                                            out_mask, out_scores, E);
}

// Round 12
// 62.209 us; speedup vs baseline: 3.1653x; 1.0268x over previous
//
#include <hip/hip_runtime.h>
#include <stdint.h>

#define G_NUM 4096
#define WPB   4                 // sel: waves per block, 1 graph per wave
#define HW    528               // hist words: 512 data (1024 u16 buckets) + skew room
#define CLSW  128               // boundary-class capacity (expected ~45)

typedef unsigned long long ull;

__device__ __forceinline__ void wsync() {
    asm volatile("s_waitcnt lgkmcnt(0)" ::: "memory");
}
__device__ __forceinline__ unsigned int order_bits(float f) {
    unsigned int b = __float_as_uint(f);
    return b ^ ((unsigned int)((int)b >> 31) | 0x80000000u);   // 3 VALU
}
// skewed word slot (strided reads spread across banks). Bijective, <HW.
__device__ __forceinline__ int HPw(int wd) { return wd + (wd >> 5); }

// ---------------- prep: start[] bsearch + gtile + mask dtype detect ----------------
__global__ void prep_kernel(const int* __restrict__ batch, int* __restrict__ start,
                            int* __restrict__ gtile, const unsigned int* __restrict__ mraw,
                            int* __restrict__ flag, int E, int ntiles) {
    if (blockIdx.x == 0 && threadIdx.x < 64) {
        int lane = threadIdx.x;
        bool allI = true, allF = true;
        for (int i = lane; i < 256; i += 64) {
            unsigned int w = mraw[i];
            if (w > 1u) allI = false;
            if (w != 0u && w != 0x3F800000u) allF = false;
        }
        allI = __all(allI);
        allF = __all(allF);
        if (lane == 0) *flag = (allI || allF) ? 0 : 2;
    }
    int t = blockIdx.x * blockDim.x + threadIdx.x;
    if (t <= G_NUM) {
        if (t == G_NUM) { start[G_NUM] = E; return; }
        int lo = 0, hi = E;
        while (lo < hi) {
            int mid = (lo + hi) >> 1;
            if (batch[mid] < t) lo = mid + 1; else hi = mid;
        }
        start[t] = lo;
    } else {
        int tt = t - (G_NUM + 1);
        if (tt < ntiles) gtile[tt] = batch[(size_t)tt << 10];
    }
}

// 512 u32-word k-th select (word==bucket). Self-clears. Also returns grand total.
__device__ __forceinline__ void wave_selw(unsigned int* hist, int lane, int kk,
                                          int& bsel, unsigned int& cgt,
                                          unsigned int& csel, unsigned int& mtot)
{
    unsigned int h[8];
    unsigned int S = 0u;
    const int b0 = lane * 8;
    #pragma unroll
    for (int j = 0; j < 8; ++j) {
        int pw = HPw(b0 + j);
        h[j] = hist[pw]; S += h[j]; hist[pw] = 0u;
    }
    unsigned int v = S;
    #pragma unroll
    for (int off = 1; off < 64; off <<= 1) {
        unsigned int o = __shfl_down(v, off, 64);
        if (lane + off < 64) v += o;
    }
    mtot = __shfl(v, 0, 64);
    unsigned int run = v - S;
    int fj = -1; unsigned int fc = 0u, fs = 0u;
    #pragma unroll
    for (int j = 7; j >= 0; --j) {
        unsigned int inc = run + h[j];
        if (fj < 0 && (unsigned)kk <= inc && (unsigned)kk > run) { fj = j; fc = run; fs = h[j]; }
        run = inc;
    }
    ull bm = __ballot(fj >= 0);
    int wl = (int)(__ffsll((long long)bm) - 1);
    bsel = __shfl(b0 + fj, wl, 64);
    cgt  = __shfl(fc, wl, 64);
    csel = __shfl(fs, wl, 64);
}

// 1024 u16-packed buckets (word b>>1, half b&1). Lane owns buckets [16*lane,+16).
__device__ __forceinline__ void wave_sel1024(unsigned int* hist, int lane, int kk,
                                             int& bsel, unsigned int& cgt, unsigned int& csel)
{
    unsigned int hw[8];
    unsigned int S = 0u;
    const int w0 = lane * 8;
    #pragma unroll
    for (int j = 0; j < 8; ++j) {
        int pw = HPw(w0 + j);
        hw[j] = hist[pw]; hist[pw] = 0u;
        S += (hw[j] & 0xFFFFu) + (hw[j] >> 16);
    }
    unsigned int v = S;
    #pragma unroll
    for (int off = 1; off < 64; off <<= 1) {
        unsigned int o = __shfl_down(v, off, 64);
        if (lane + off < 64) v += o;
    }
    unsigned int run = v - S;
    int fj = -1; unsigned int fc = 0u, fs = 0u;
    #pragma unroll
    for (int j = 15; j >= 0; --j) {
        unsigned int c = (j & 1) ? (hw[j >> 1] >> 16) : (hw[j >> 1] & 0xFFFFu);
        unsigned int inc = run + c;
        if (fj < 0 && (unsigned)kk <= inc && (unsigned)kk > run) { fj = j; fc = run; fs = c; }
        run = inc;
    }
    ull bm = __ballot(fj >= 0);
    int wl = (int)(__ffsll((long long)bm) - 1);
    bsel = __shfl(lane * 16 + fj, wl, 64);
    cgt  = __shfl(fc, wl, 64);
    csel = __shfl(fs, wl, 64);
}

// ---------------- sel: per-graph exact (P, licut), zero barriers, lean ----------------
__global__ __launch_bounds__(256, 8) void sel_kernel(
    const float* __restrict__ scores, const void* __restrict__ maskp,
    const int* __restrict__ start, const int* __restrict__ kp,
    const int* __restrict__ flagp, ull* __restrict__ PL)
{
    __shared__ unsigned int hist_s[WPB][HW];
    __shared__ ull          cls_s[WPB][CLSW];
    __shared__ unsigned int ccnt_s[WPB];

    const int lane = threadIdx.x & 63;
    const int w    = threadIdx.x >> 6;
    const int g    = blockIdx.x * WPB + w;

    const int s0 = start[g], s1 = start[g + 1], len = s1 - s0;
    if (len <= 0) return;                       // empty: never queried by out
    const int k = *kp, mflag = *flagp;
    if (k <= 0) { if (!lane) PL[g] = ~0ull; return; }

    unsigned int* hist = hist_s[w];
    ull*          cls  = cls_s[w];

    const int a0  = s0 & ~3;
    const int nch = (s1 - a0 + 255) >> 8;
    const bool byteMask = (mflag == 2);

    #pragma unroll
    for (int j = 0; j < 9; ++j) { int idx = lane + 64 * j; if (idx < HW) hist[idx] = 0u; }
    if (!lane) ccnt_s[w] = 0u;
    wsync();

    // lean chunk loader: full chunks unguarded; only the s1-straddling chunk is guarded
    auto load4 = [&](int g0, float* pf) -> unsigned int {
        unsigned int cb = 0u;                  // bit e set if mask nonzero at elem e
        if (g0 + 4 <= s1) {
            *(float4*)pf = *(const float4*)(scores + g0);
            if (byteMask) {
                unsigned int mw = *(const unsigned int*)((const unsigned char*)maskp + g0);
                cb = ((mw & 0xFFu) ? 1u : 0u) | ((mw & 0xFF00u) ? 2u : 0u) |
                     ((mw & 0xFF0000u) ? 4u : 0u) | ((mw & 0xFF000000u) ? 8u : 0u);
            } else {
                int4 mw = *(const int4*)((const int*)maskp + g0);
                cb = (mw.x ? 1u : 0u) | (mw.y ? 2u : 0u) | (mw.z ? 4u : 0u) | (mw.w ? 8u : 0u);
            }
        } else {
            #pragma unroll
            for (int e = 0; e < 4; ++e) {
                int gi = g0 + e; pf[e] = 0.0f;
                if (gi < s1) {
                    pf[e] = scores[gi];
                    bool c = byteMask ? (((const unsigned char*)maskp)[gi] != 0)
                                      : (((const int*)maskp)[gi] != 0);
                    if (c) cb |= 1u << e;
                }
            }
        }
        return cb;
    };

    // ---- sweep 1: packed u16 histogram over 10-bit buckets ----
    unsigned int P = 0u;
    int licut = 0x7FFFFFFF;
    bool big = (len > 30000);                  // u16-count overflow guard (never here)

    if (!big) {
        int lc = 0;
        for (int q = 0; q < nch; ++q) {
            const int g0 = a0 + 4 * (q * 64 + lane);
            float f4[4];
            unsigned int cb = load4(g0, f4);
            #pragma unroll
            for (int e = 0; e < 4; ++e) {
                int li = g0 + e - s0;
                bool cand = ((cb >> e) & 1u) && li >= 0;
                if (cand) {
                    unsigned int ob = order_bits(f4[e]);
                    atomicAdd(&hist[HPw((int)(ob >> 23))], 1u << (((ob >> 22) & 1u) << 4));
                    ++lc;
                }
            }
        }
        #pragma unroll
        for (int off = 1; off < 64; off <<= 1) lc += __shfl_xor(lc, off, 64);
        wsync();

        if (lc > k) {
            int bsel; unsigned int cgt, csel;
            wave_sel1024(hist, lane, k, bsel, cgt, csel);
            int kk2 = k - (int)cgt;

            if (csel <= CLSW) {
                // ---- sweep 2 (L2-hot): collect boundary class ----
                for (int q = 0; q < nch; ++q) {
                    const int g0 = a0 + 4 * (q * 64 + lane);
                    float f4[4];
                    unsigned int cb = load4(g0, f4);
                    #pragma unroll
                    for (int e = 0; e < 4; ++e) {
                        int li = g0 + e - s0;
                        if (((cb >> e) & 1u) && li >= 0) {
                            unsigned int ob = order_bits(f4[e]);
                            if ((int)(ob >> 22) == bsel) {
                                unsigned int idx = atomicAdd(&ccnt_s[w], 1u);
                                if (idx < CLSW) cls[idx] = ((ull)ob << 32) | (unsigned)li;
                            }
                        }
                    }
                }
                wsync();
                bool found = false; unsigned int fP = 0u; int fL = 0;
                if (csel <= 64) {
                    ull me = (lane < (int)csel) ? cls[lane] : 0ull;
                    unsigned int mk = (unsigned int)(me >> 32), ml = (unsigned int)me;
                    int r = 0;
                    for (int j = 0; j < (int)csel; ++j) {
                        ull o = __shfl(me, j, 64);
                        unsigned int ok = (unsigned int)(o >> 32), ol = (unsigned int)o;
                        r += (ok > mk || (ok == mk && ol < ml)) ? 1 : 0;
                    }
                    if (lane < (int)csel && r == kk2 - 1) { found = true; fP = mk; fL = (int)ml; }
                } else {
                    for (int e = lane; e < (int)csel; e += 64) {
                        ull me = cls[e];
                        unsigned int mk = (unsigned int)(me >> 32), ml = (unsigned int)me;
                        int r = 0;
                        for (int j = 0; j < (int)csel; ++j) {
                            ull o = cls[j];
                            unsigned int ok = (unsigned int)(o >> 32), ol = (unsigned int)o;
                            r += (ok > mk || (ok == mk && ol < ml)) ? 1 : 0;
                        }
                        if (r == kk2 - 1) { found = true; fP = mk; fL = (int)ml; }
                    }
                }
                ull bm = __ballot(found);
                int wl = (int)(__ffsll((long long)bm) - 1);
                P = __shfl(fP, wl, 64); licut = __shfl(fL, wl, 64);
            } else {
                big = true;                    // rare: huge tie class -> exact radix path
            }
        }
        // lc <= k: keepall (P=0, licut=max) — all candidates kept
    }

    if (big) {
        // ---- exact 4-round u32 radix over 512-word hist: 9/9/9/5 bits ----
        const int shifts[4] = {23, 14, 5, 0};
        const int widths[4] = {9, 9, 9, 5};
        unsigned int pfx = 0u;
        int kk2 = k;
        bool keepall = false;
        wsync();
        for (int r = 0; r < 4 && !keepall; ++r) {
            const int L = shifts[r], W = widths[r];
            const unsigned int dm = (1u << W) - 1u;
            const int hi = L + W;
            for (int q = 0; q < nch; ++q) {
                const int g0 = a0 + 4 * (q * 64 + lane);
                float f4[4];
                unsigned int cb = load4(g0, f4);
                #pragma unroll
                for (int e = 0; e < 4; ++e) {
                    int li = g0 + e - s0;
                    if (((cb >> e) & 1u) && li >= 0) {
                        unsigned int ob = order_bits(f4[e]);
                        if (r == 0 || (ob >> hi) == (pfx >> hi))
                            atomicAdd(&hist[HPw((int)((ob >> L) & dm))], 1u);
                    }
                }
            }
            wsync();
            int b2; unsigned int cg2, cs2, mt2;
            wave_selw(hist, lane, kk2, b2, cg2, cs2, mt2);
            if (r == 0 && mt2 <= (unsigned)k) { keepall = true; break; }
            pfx |= ((unsigned int)b2) << L;
            kk2 -= (int)cg2;
        }
        if (!keepall) {
            P = pfx;
            int lo2 = 0, hi2 = len - 1;        // li binary search among ob == P
            while (lo2 < hi2) {
                int mid = (lo2 + hi2) >> 1;
                int cc = 0;
                for (int q = 0; q < nch; ++q) {
                    const int g0 = a0 + 4 * (q * 64 + lane);
                    float f4[4];
                    unsigned int cb = load4(g0, f4);
                    #pragma unroll
                    for (int e = 0; e < 4; ++e) {
                        int li = g0 + e - s0;
                        if (((cb >> e) & 1u) && li >= 0 && li <= mid &&
                            order_bits(f4[e]) == P) ++cc;
                    }
                }
                #pragma unroll
                for (int off = 1; off < 64; off <<= 1) cc += __shfl_xor(cc, off, 64);
                if (cc >= kk2) hi2 = mid; else lo2 = mid + 1;
            }
            licut = lo2;
        } else {
            P = 0u; licut = 0x7FFFFFFF;
        }
    }

    if (!lane) PL[g] = ((ull)P << 32) | (unsigned int)licut;
}

// ---------------- out: pure streaming map (no LDS, no atomics, no barriers) ----------------
__global__ __launch_bounds__(256) void out_kernel(
    const float* __restrict__ scores, const void* __restrict__ maskp,
    const int* __restrict__ start, const int* __restrict__ gtile,
    const ull* __restrict__ PL, const int* __restrict__ flagp,
    float* __restrict__ out_mask, float* __restrict__ out_scores, int E)
{
    const int mflag = *flagp;
    const int nchunk = E >> 2;
    const int stride = gridDim.x * blockDim.x;
    for (int c = blockIdx.x * blockDim.x + threadIdx.x; c < nchunk; c += stride) {
        const int gi0 = c << 2;
        int g = gtile[gi0 >> 10];
        int sg = start[g], snext = start[g + 1];
        while (gi0 >= snext) { ++g; sg = snext; snext = start[g + 1]; }
        ull pl = PL[g];

        float4 f = *(const float4*)(scores + gi0);
        unsigned int cm4 = 0u;
        if (mflag == 2) {
            unsigned int mw = *(const unsigned int*)((const unsigned char*)maskp + gi0);
            if (mw & 0x000000FFu) cm4 |= 1u;
            if (mw & 0x0000FF00u) cm4 |= 2u;
            if (mw & 0x00FF0000u) cm4 |= 4u;
            if (mw & 0xFF000000u) cm4 |= 8u;
        } else {
            int4 mw = *(const int4*)((const int*)maskp + gi0);
            if (mw.x) cm4 |= 1u; if (mw.y) cm4 |= 2u;
            if (mw.z) cm4 |= 4u; if (mw.w) cm4 |= 8u;
        }
        float4 vm, vs;
        float* pm = (float*)&vm; float* ps = (float*)&vs;
        const float* pf = (const float*)&f;
        #pragma unroll
        for (int j = 0; j < 4; ++j) {
            int gi = gi0 + j;
            while (gi >= snext) { ++g; sg = snext; snext = start[g + 1]; pl = PL[g]; }
            unsigned int Pv = (unsigned int)(pl >> 32);
            int Lv = (int)(unsigned int)pl;
            unsigned int key = order_bits(pf[j]);
            int li = gi - sg;
            bool kept = ((cm4 >> j) & 1u) && (key > Pv || (key == Pv && li <= Lv));
            pm[j] = kept ? 1.0f : 0.0f;
            ps[j] = kept ? pf[j] : 0.0f;
        }
        *(float4*)(out_mask   + gi0) = vm;
        *(float4*)(out_scores + gi0) = vs;
    }
    if (blockIdx.x == 0 && threadIdx.x == 0 && (E & 3)) {
        for (int gi = E & ~3; gi < E; ++gi) {
            int g = gtile[gi >> 10];
            while (gi >= start[g + 1]) ++g;
            ull pl = PL[g];
            unsigned int Pv = (unsigned int)(pl >> 32);
            int Lv = (int)(unsigned int)pl;
            bool cand = (mflag == 2) ? (((const unsigned char*)maskp)[gi] != 0)
                                     : (((const int*)maskp)[gi] != 0);
            float sc = scores[gi];
            unsigned int key = order_bits(sc);
            int li = gi - start[g];
            bool kept = cand && (key > Pv || (key == Pv && li <= Lv));
            out_mask[gi]   = kept ? 1.0f : 0.0f;
            out_scores[gi] = kept ? sc : 0.0f;
        }
    }
}

extern "C" void kernel_launch(void* const* d_in, const int* in_sizes, int n_in,
                              void* d_out, int out_size, void* d_ws, size_t ws_size,
                              hipStream_t stream) {
    const float* scores = (const float*)d_in[0];
    const int*   batch  = (const int*)d_in[1];
    const void*  mask   = d_in[2];
    const int*   kp     = (const int*)d_in[4];
    const int    E      = in_sizes[0];

    float* out_mask   = (float*)d_out;
    float* out_scores = out_mask + E;

    const int ntiles = (E + 1023) >> 10;
    char* ws = (char*)d_ws;
    int* flag  = (int*)ws;
    int* start = (int*)(ws + 4096);
    int* gtile = (int*)(ws + 4096 + 16640);
    ull* PL    = (ull*)(ws + 4096 + 16640 + (((size_t)ntiles * 4 + 255) & ~(size_t)255));

    const int prep_threads = G_NUM + 1 + ntiles;
    prep_kernel<<<(prep_threads + 255) / 256, 256, 0, stream>>>(
        batch, start, gtile, (const unsigned int*)mask, flag, E, ntiles);
    sel_kernel<<<G_NUM / WPB, 256, 0, stream>>>(scores, mask, start, kp, flag, PL);
    const int nchunk = E >> 2;
    int oblocks = (nchunk + 255) / 256;
    if (oblocks > 2048) oblocks = 2048;
    out_kernel<<<oblocks, 256, 0, stream>>>(scores, mask, start, gtile, PL, flag,
                                            out_mask, out_scores, E);
}

// Round 13
// 59.052 us; speedup vs baseline: 3.3345x; 1.0535x over previous
//
#include <hip/hip_runtime.h>
#include <stdint.h>

#define G_NUM 4096
#define HW    528               // hist words: 512 data (1024 u16 buckets) + skew room
#define CLSW  128               // boundary-class capacity (expected ~45)
#define KELEM 4096              // staged u16 keys per block (covers len<=4096; ~45 sigma)

typedef unsigned long long ull;

__device__ __forceinline__ unsigned int order_bits(float f) {
    unsigned int b = __float_as_uint(f);
    return b ^ ((unsigned int)((int)b >> 31) | 0x80000000u);
}
// skewed word slot (strided reads spread across banks). Bijective, <HW.
__device__ __forceinline__ int HPw(int wd) { return wd + (wd >> 5); }

// ---------------- prep: start[] bsearch + gtile + mask dtype detect ----------------
__global__ void prep_kernel(const int* __restrict__ batch, int* __restrict__ start,
                            int* __restrict__ gtile, const unsigned int* __restrict__ mraw,
                            int* __restrict__ flag, int E, int ntiles) {
    if (blockIdx.x == 0 && threadIdx.x < 64) {
        int lane = threadIdx.x;
        bool allI = true, allF = true;
        for (int i = lane; i < 256; i += 64) {
            unsigned int w = mraw[i];
            if (w > 1u) allI = false;
            if (w != 0u && w != 0x3F800000u) allF = false;
        }
        allI = __all(allI);
        allF = __all(allF);
        if (lane == 0) *flag = (allI || allF) ? 0 : 2;
    }
    int t = blockIdx.x * blockDim.x + threadIdx.x;
    if (t <= G_NUM) {
        if (t == G_NUM) { start[G_NUM] = E; return; }
        int lo = 0, hi = E;
        while (lo < hi) {
            int mid = (lo + hi) >> 1;
            if (batch[mid] < t) lo = mid + 1; else hi = mid;
        }
        start[t] = lo;
    } else {
        int tt = t - (G_NUM + 1);
        if (tt < ntiles) gtile[tt] = batch[(size_t)tt << 10];
    }
}

// 512 u32-word k-th select (word==bucket, skew-mapped). Wave-level, self-clears.
__device__ __forceinline__ void wave_selw(unsigned int* hist, int lane, int kk,
                                          int& bsel, unsigned int& cgt, unsigned int& csel)
{
    unsigned int h[8];
    unsigned int S = 0u;
    const int b0 = lane * 8;
    #pragma unroll
    for (int j = 0; j < 8; ++j) {
        int pw = HPw(b0 + j);
        h[j] = hist[pw]; S += h[j]; hist[pw] = 0u;
    }
    unsigned int v = S;
    #pragma unroll
    for (int off = 1; off < 64; off <<= 1) {
        unsigned int o = __shfl_down(v, off, 64);
        if (lane + off < 64) v += o;
    }
    unsigned int run = v - S;
    int fj = -1; unsigned int fc = 0u, fs = 0u;
    #pragma unroll
    for (int j = 7; j >= 0; --j) {
        unsigned int inc = run + h[j];
        if (fj < 0 && (unsigned)kk <= inc && (unsigned)kk > run) { fj = j; fc = run; fs = h[j]; }
        run = inc;
    }
    ull bm = __ballot(fj >= 0);
    int wl = (int)(__ffsll((long long)bm) - 1);
    bsel = __shfl(b0 + fj, wl, 64);
    cgt  = __shfl(fc, wl, 64);
    csel = __shfl(fs, wl, 64);
}

// 1024 u16-packed buckets (word b>>1, half via bit16 shift). Wave-level, self-clears.
__device__ __forceinline__ void wave_sel1024(unsigned int* hist, int lane, int kk,
                                             int& bsel, unsigned int& cgt, unsigned int& csel)
{
    unsigned int hw[8];
    unsigned int S = 0u;
    const int w0 = lane * 8;
    #pragma unroll
    for (int j = 0; j < 8; ++j) {
        int pw = HPw(w0 + j);
        hw[j] = hist[pw]; hist[pw] = 0u;
        S += (hw[j] & 0xFFFFu) + (hw[j] >> 16);
    }
    unsigned int v = S;
    #pragma unroll
    for (int off = 1; off < 64; off <<= 1) {
        unsigned int o = __shfl_down(v, off, 64);
        if (lane + off < 64) v += o;
    }
    unsigned int run = v - S;
    int fj = -1; unsigned int fc = 0u, fs = 0u;
    #pragma unroll
    for (int j = 15; j >= 0; --j) {
        unsigned int c = (j & 1) ? (hw[j >> 1] >> 16) : (hw[j >> 1] & 0xFFFFu);
        unsigned int inc = run + c;
        if (fj < 0 && (unsigned)kk <= inc && (unsigned)kk > run) { fj = j; fc = run; fs = c; }
        run = inc;
    }
    ull bm = __ballot(fj >= 0);
    int wl = (int)(__ffsll((long long)bm) - 1);
    bsel = __shfl(lane * 16 + fj, wl, 64);
    cgt  = __shfl(fc, wl, 64);
    csel = __shfl(fs, wl, 64);
}

// ---------------- sel: 1 block (4 waves) per graph, 3 barriers ----------------
__global__ __launch_bounds__(256, 8) void sel_kernel(
    const float* __restrict__ scores, const void* __restrict__ maskp,
    const int* __restrict__ start, const int* __restrict__ kp,
    const int* __restrict__ flagp, ull* __restrict__ PL)
{
    __shared__ unsigned short k16[KELEM];
    __shared__ unsigned int   hist[HW];
    __shared__ ull            cls[CLSW];
    __shared__ unsigned int   ccnt;
    __shared__ int            mcnt;
    __shared__ int            bc_bsel;
    __shared__ unsigned int   bc_cgt, bc_csel;

    const int tid  = threadIdx.x;
    const int lane = tid & 63;
    const int g    = blockIdx.x;

    const int s0 = start[g], s1 = start[g + 1], len = s1 - s0;
    if (len <= 0) return;                       // empty: never queried by out
    const int k = *kp, mflag = *flagp;
    if (k <= 0) { if (!tid) PL[g] = ~0ull; return; }   // P=max, licut=-1 -> keep none

    const int a0  = s0 & ~3;
    const int dl  = a0 - s0;
    const int total = s1 - a0;
    const int nq  = (total + 1023) >> 10;       // 1024-elem block chunks
    const bool st16 = (total <= KELEM);
    const bool byteMask = (mflag == 2);

    for (int j = tid; j < HW; j += 256) hist[j] = 0u;
    if (!tid) { ccnt = 0u; mcnt = 0; }
    __syncthreads();                            // B1

    // guarded 4-elem loader
    auto load4 = [&](int g0, float* pf) -> unsigned int {
        unsigned int cb = 0u;
        if (g0 >= s0 && g0 + 4 <= s1) {
            *(float4*)pf = *(const float4*)(scores + g0);
            if (byteMask) {
                unsigned int mw = *(const unsigned int*)((const unsigned char*)maskp + g0);
                cb = ((mw & 0xFFu) ? 1u : 0u) | ((mw & 0xFF00u) ? 2u : 0u) |
                     ((mw & 0xFF0000u) ? 4u : 0u) | ((mw & 0xFF000000u) ? 8u : 0u);
            } else {
                int4 mw = *(const int4*)((const int*)maskp + g0);
                cb = (mw.x ? 1u : 0u) | (mw.y ? 2u : 0u) | (mw.z ? 4u : 0u) | (mw.w ? 8u : 0u);
            }
        } else {
            #pragma unroll
            for (int e = 0; e < 4; ++e) {
                int gi = g0 + e; pf[e] = 0.0f;
                if (gi >= s0 && gi < s1) {
                    pf[e] = scores[gi];
                    bool c = byteMask ? (((const unsigned char*)maskp)[gi] != 0)
                                      : (((const int*)maskp)[gi] != 0);
                    if (c) cb |= 1u << e;
                }
            }
        }
        return cb;
    };

    // ---- sweep 1 (only global pass): histogram + k16 staging + count ----
    int lc = 0;
    for (int q = 0; q < nq; ++q) {
        const int g0 = a0 + (q << 10) + 4 * tid;
        float f4[4];
        unsigned int cb = load4(g0, f4);
        ushort4 hv; unsigned short* hp = (unsigned short*)&hv;
        #pragma unroll
        for (int e = 0; e < 4; ++e) {
            unsigned int ob = order_bits(f4[e]);
            unsigned int h = ob >> 16; h += (h == 0u);          // cand sentinel >=1
            bool cand = (cb >> e) & 1u;
            hp[e] = cand ? (unsigned short)h : (unsigned short)0;
            if (cand) {
                atomicAdd(&hist[HPw((int)(ob >> 23))], 1u << (((ob >> 22) & 1u) << 4));
                ++lc;
            }
        }
        if (st16) *(ushort4*)&k16[(q << 10) + 4 * tid] = hv;
    }
    #pragma unroll
    for (int off = 1; off < 64; off <<= 1) lc += __shfl_xor(lc, off, 64);
    if (!lane) atomicAdd(&mcnt, lc);
    __syncthreads();                            // B2
    const int m = mcnt;

    if (m <= k) { if (!tid) PL[g] = 0x7FFFFFFFull; return; }   // keepall

    // ---- k-th bucket select (wave 0), broadcast ----
    if (tid < 64) {
        int bsel; unsigned int cgt, csel;
        wave_sel1024(hist, lane, k, bsel, cgt, csel);
        if (!lane) { bc_bsel = bsel; bc_cgt = cgt; bc_csel = csel; }
    }
    __syncthreads();                            // B3
    const int bsel = bc_bsel;
    int kk2 = k - (int)bc_cgt;
    const unsigned int csel = bc_csel;

    unsigned int P = 0u;
    int licut = 0x7FFFFFFF;

    if (csel <= CLSW) {
        // ---- collect boundary class ----
        if (st16) {
            const unsigned int* kw = (const unsigned int*)k16;
            const int nw = nq << 9;             // u32 words staged
            for (int i2 = tid; i2 < nw; i2 += 256) {
                unsigned int h2 = kw[i2];
                unsigned int h0 = h2 & 0xFFFFu, h1 = h2 >> 16;
                if (h0 && (int)(h0 >> 6) == bsel) {
                    int lp = 2 * i2;
                    unsigned int key = order_bits(scores[a0 + lp]);
                    unsigned int idx = atomicAdd(&ccnt, 1u);
                    if (idx < CLSW) cls[idx] = ((ull)key << 32) | (unsigned)(lp + dl);
                }
                if (h1 && (int)(h1 >> 6) == bsel) {
                    int lp = 2 * i2 + 1;
                    unsigned int key = order_bits(scores[a0 + lp]);
                    unsigned int idx = atomicAdd(&ccnt, 1u);
                    if (idx < CLSW) cls[idx] = ((ull)key << 32) | (unsigned)(lp + dl);
                }
            }
        } else {
            for (int q = 0; q < nq; ++q) {
                const int g0 = a0 + (q << 10) + 4 * tid;
                float f4[4];
                unsigned int cb = load4(g0, f4);
                #pragma unroll
                for (int e = 0; e < 4; ++e) {
                    if ((cb >> e) & 1u) {
                        unsigned int ob = order_bits(f4[e]);
                        if ((int)(ob >> 22) == bsel) {
                            unsigned int idx = atomicAdd(&ccnt, 1u);
                            if (idx < CLSW) cls[idx] = ((ull)ob << 32) | (unsigned)(g0 + e - s0);
                        }
                    }
                }
            }
        }
        __syncthreads();                        // B4: cls ready
        // ---- exact rank by (key desc, li asc), wave 0 ----
        if (tid < 64) {
            bool found = false; unsigned int fP = 0u; int fL = 0;
            for (int e = lane; e < (int)csel; e += 64) {
                ull me = cls[e];
                unsigned int mk = (unsigned int)(me >> 32), ml = (unsigned int)me;
                int r = 0;
                for (int j = 0; j < (int)csel; ++j) {
                    ull o = cls[j];
                    unsigned int ok = (unsigned int)(o >> 32), ol = (unsigned int)o;
                    r += (ok > mk || (ok == mk && ol < ml)) ? 1 : 0;
                }
                if (r == kk2 - 1) { found = true; fP = mk; fL = (int)ml; }
            }
            ull bm = __ballot(found);
            int wl = (int)(__ffsll((long long)bm) - 1);
            P = __shfl(fP, wl, 64); licut = __shfl(fL, wl, 64);
            if (!lane) PL[g] = ((ull)P << 32) | (unsigned int)licut;
        }
        return;
    }

    // ---- degenerate: >CLSW in selected bucket. Refine bits [21:0]: 9/9/4 ----
    {
        unsigned int pfx = ((unsigned int)bsel) << 22;
        const int lows[3] = {13, 4, 0};
        const int wids[3] = {9, 9, 4};
        for (int r = 0; r < 3; ++r) {
            const int L = lows[r], W = wids[r];
            const unsigned int dm = (1u << W) - 1u;
            const int hb = L + W;
            for (int q = 0; q < nq; ++q) {
                const int g0 = a0 + (q << 10) + 4 * tid;
                float f4[4];
                unsigned int cb = load4(g0, f4);
                #pragma unroll
                for (int e = 0; e < 4; ++e) {
                    if ((cb >> e) & 1u) {
                        unsigned int ob = order_bits(f4[e]);
                        if ((ob >> hb) == (pfx >> hb))
                            atomicAdd(&hist[HPw((int)((ob >> L) & dm))], 1u);
                    }
                }
            }
            __syncthreads();
            if (tid < 64) {
                int b2; unsigned int cg2, cs2;
                wave_selw(hist, lane, kk2, b2, cg2, cs2);
                if (!lane) { bc_bsel = b2; bc_cgt = cg2; }
            }
            __syncthreads();
            pfx |= ((unsigned int)bc_bsel) << L;
            kk2 -= (int)bc_cgt;
        }
        P = pfx;
        // li binary search among ob == P (huge tie class)
        int lo2 = 0, hi2 = len - 1;
        while (lo2 < hi2) {
            int mid = (lo2 + hi2) >> 1;
            if (!tid) mcnt = 0;
            __syncthreads();
            int cc = 0;
            for (int q = 0; q < nq; ++q) {
                const int g0 = a0 + (q << 10) + 4 * tid;
                float f4[4];
                unsigned int cb = load4(g0, f4);
                #pragma unroll
                for (int e = 0; e < 4; ++e) {
                    int li = g0 + e - s0;
                    if (((cb >> e) & 1u) && li <= mid && order_bits(f4[e]) == P) ++cc;
                }
            }
            #pragma unroll
            for (int off = 1; off < 64; off <<= 1) cc += __shfl_xor(cc, off, 64);
            if (!lane) atomicAdd(&mcnt, cc);
            __syncthreads();
            if (mcnt >= kk2) hi2 = mid; else lo2 = mid + 1;
            __syncthreads();
        }
        licut = lo2;
        if (!tid) PL[g] = ((ull)P << 32) | (unsigned int)licut;
    }
}

// ---------------- out: pure streaming map (no LDS, no atomics, no barriers) ----------------
__global__ __launch_bounds__(256) void out_kernel(
    const float* __restrict__ scores, const void* __restrict__ maskp,
    const int* __restrict__ start, const int* __restrict__ gtile,
    const ull* __restrict__ PL, const int* __restrict__ flagp,
    float* __restrict__ out_mask, float* __restrict__ out_scores, int E)
{
    const int mflag = *flagp;
    const int nchunk = E >> 2;
    const int stride = gridDim.x * blockDim.x;
    for (int c = blockIdx.x * blockDim.x + threadIdx.x; c < nchunk; c += stride) {
        const int gi0 = c << 2;
        int g = gtile[gi0 >> 10];
        int sg = start[g], snext = start[g + 1];
        while (gi0 >= snext) { ++g; sg = snext; snext = start[g + 1]; }
        ull pl = PL[g];

        float4 f = *(const float4*)(scores + gi0);
        unsigned int cm4 = 0u;
        if (mflag == 2) {
            unsigned int mw = *(const unsigned int*)((const unsigned char*)maskp + gi0);
            if (mw & 0x000000FFu) cm4 |= 1u;
            if (mw & 0x0000FF00u) cm4 |= 2u;
            if (mw & 0x00FF0000u) cm4 |= 4u;
            if (mw & 0xFF000000u) cm4 |= 8u;
        } else {
            int4 mw = *(const int4*)((const int*)maskp + gi0);
            if (mw.x) cm4 |= 1u; if (mw.y) cm4 |= 2u;
            if (mw.z) cm4 |= 4u; if (mw.w) cm4 |= 8u;
        }
        float4 vm, vs;
        float* pm = (float*)&vm; float* ps = (float*)&vs;
        const float* pf = (const float*)&f;
        #pragma unroll
        for (int j = 0; j < 4; ++j) {
            int gi = gi0 + j;
            while (gi >= snext) { ++g; sg = snext; snext = start[g + 1]; pl = PL[g]; }
            unsigned int Pv = (unsigned int)(pl >> 32);
            int Lv = (int)(unsigned int)pl;
            unsigned int key = order_bits(pf[j]);
            int li = gi - sg;
            bool kept = ((cm4 >> j) & 1u) && (key > Pv || (key == Pv && li <= Lv));
            pm[j] = kept ? 1.0f : 0.0f;
            ps[j] = kept ? pf[j] : 0.0f;
        }
        *(float4*)(out_mask   + gi0) = vm;
        *(float4*)(out_scores + gi0) = vs;
    }
    if (blockIdx.x == 0 && threadIdx.x == 0 && (E & 3)) {
        for (int gi = E & ~3; gi < E; ++gi) {
            int g = gtile[gi >> 10];
            while (gi >= start[g + 1]) ++g;
            ull pl = PL[g];
            unsigned int Pv = (unsigned int)(pl >> 32);
            int Lv = (int)(unsigned int)pl;
            bool cand = (mflag == 2) ? (((const unsigned char*)maskp)[gi] != 0)
                                     : (((const int*)maskp)[gi] != 0);
            float sc = scores[gi];
            unsigned int key = order_bits(sc);
            int li = gi - start[g];
            bool kept = cand && (key > Pv || (key == Pv && li <= Lv));
            out_mask[gi]   = kept ? 1.0f : 0.0f;
            out_scores[gi] = kept ? sc : 0.0f;
        }
    }
}

extern "C" void kernel_launch(void* const* d_in, const int* in_sizes, int n_in,
                              void* d_out, int out_size, void* d_ws, size_t ws_size,
                              hipStream_t stream) {
    const float* scores = (const float*)d_in[0];
    const int*   batch  = (const int*)d_in[1];
    const void*  mask   = d_in[2];
    const int*   kp     = (const int*)d_in[4];
    const int    E      = in_sizes[0];

    float* out_mask   = (float*)d_out;
    float* out_scores = out_mask + E;

    const int ntiles = (E + 1023) >> 10;
    char* ws = (char*)d_ws;
    int* flag  = (int*)ws;
    int* start = (int*)(ws + 4096);
    int* gtile = (int*)(ws + 4096 + 16640);
    ull* PL    = (ull*)(ws + 4096 + 16640 + (((size_t)ntiles * 4 + 255) & ~(size_t)255));

    const int prep_threads = G_NUM + 1 + ntiles;
    prep_kernel<<<(prep_threads + 255) / 256, 256, 0, stream>>>(
        batch, start, gtile, (const unsigned int*)mask, flag, E, ntiles);
    sel_kernel<<<G_NUM, 256, 0, stream>>>(scores, mask, start, kp, flag, PL);
    const int nchunk = E >> 2;
    int oblocks = (nchunk + 255) / 256;
    if (oblocks > 2048) oblocks = 2048;
    out_kernel<<<oblocks, 256, 0, stream>>>(scores, mask, start, gtile, PL, flag,
                                            out_mask, out_scores, E);
}